// Round 5
// baseline (135.262 us; speedup 1.0000x reference)
//
#include <hip/hip_runtime.h>
#include <hip/hip_bf16.h>

// MHA fwd: B=2, S=2048, D=256, H=8, Dh=32.
// Outputs: out [2,2048,256] fp32, attn_mean [2,2048,2048] fp32 (concat in d_out).
//
// R12: q64 tiles in both S^2 kernels (second doubling of K-reuse).
// Ledger: only memory-work reduction pays (R9 -6.8us/32MB HBM, R11 -7.2us
// for halved L2 re-reads). q32->q64: flash 4 loads feed 16 MFMAs (was 8);
// attn_write 8 loads feed 16 MFMAs (was 6/8). Registers stay under the
// spill cliff (flash ~140, attn ~170 est). setprio dropped (null, R8/R10).
// Grids: flash 512, attn_out 256+512; XCD-chunked swizzle kept (free).

#define B_   2
#define S_   2048
#define D_   256
#define H_   8
#define DH_  32
#define NROW (B_*S_)      // 4096
#define KSPLIT 4
#define KKEYS (S_/KSPLIT) // 512

typedef __attribute__((ext_vector_type(8))) short bf16x8;  // 8 bf16 (4 VGPRs)
typedef __attribute__((ext_vector_type(4))) float f32x4;

__device__ __forceinline__ f32x4 mfma_bf16(bf16x8 a, bf16x8 b, f32x4 c) {
    return __builtin_amdgcn_mfma_f32_16x16x32_bf16(a, b, c, 0, 0, 0);
}

__device__ __forceinline__ float fast_exp2(float x) {
    return __builtin_amdgcn_exp2f(x);   // v_exp_f32
}

__device__ __forceinline__ unsigned short f2bf_bits(float v) {
    __hip_bfloat16 h = __float2bfloat16(v);
    return *reinterpret_cast<unsigned short*>(&h);
}

// fragment-linear index for a row-major [R x 256] matrix element (m, k)
__device__ __forceinline__ size_t fragidx(int m, int k) {
    return (size_t)(m >> 4) * 4096 + (k >> 5) * 512 + ((k >> 3) & 3) * 128
           + (m & 15) * 8 + (k & 7);
}

// ---------------- split fp32 -> (hi, lo) bf16, fragment-linear, one launch ----------------
__global__ void split_all(const float4* __restrict__ x,
                          const float4* __restrict__ wq, const float4* __restrict__ wk,
                          const float4* __restrict__ wv, const float4* __restrict__ wc,
                          ushort4* __restrict__ xh, ushort4* __restrict__ xl,
                          ushort4* __restrict__ wqh, ushort4* __restrict__ wql,
                          ushort4* __restrict__ wkh, ushort4* __restrict__ wkl,
                          ushort4* __restrict__ wvh, ushort4* __restrict__ wvl,
                          ushort4* __restrict__ wch, ushort4* __restrict__ wcl) {
    int i = blockIdx.x * 256 + threadIdx.x;   // total 327680 float4s
    const float4* src; ushort4 *ph, *pl; int off;
    if (i < 262144) { src = x; ph = xh; pl = xl; off = i; }
    else {
        int j = i - 262144;
        int rg = j >> 14; off = j & 16383;
        if (rg == 0)      { src = wq; ph = wqh; pl = wql; }
        else if (rg == 1) { src = wk; ph = wkh; pl = wkl; }
        else if (rg == 2) { src = wv; ph = wvh; pl = wvl; }
        else              { src = wc; ph = wch; pl = wcl; }
    }
    float4 v = src[off];
    float vv[4] = {v.x, v.y, v.z, v.w};
    ushort4 hb, lb;
    unsigned short* hp = (unsigned short*)&hb;
    unsigned short* lp = (unsigned short*)&lb;
    for (int c = 0; c < 4; c++) {
        __hip_bfloat16 h = __float2bfloat16(vv[c]);
        hp[c] = *reinterpret_cast<unsigned short*>(&h);
        lp[c] = f2bf_bits(vv[c] - __bfloat162float(h));
    }
    int m = off >> 6, k = (off & 63) * 4;
    size_t fi = fragidx(m, k);          // divisible by 4
    ph[fi >> 2] = hb;
    pl[fi >> 2] = lb;
}

// ---------------- QKV projection: y = x @ W^T + b ----------------
// grid (NROW/64=64, 4, 3), block 256 (4 waves, 2x2 wave tiles of 32x32).
__global__ __launch_bounds__(256) void qkv_gemm(
    const __hip_bfloat16* __restrict__ xh, const __hip_bfloat16* __restrict__ xl,
    const __hip_bfloat16* __restrict__ w0h, const __hip_bfloat16* __restrict__ w0l,
    const __hip_bfloat16* __restrict__ w1h, const __hip_bfloat16* __restrict__ w1l,
    const __hip_bfloat16* __restrict__ w2h, const __hip_bfloat16* __restrict__ w2l,
    const float* __restrict__ bq, const float* __restrict__ bk, const float* __restrict__ bvv,
    __hip_bfloat16* __restrict__ Qf, __hip_bfloat16* __restrict__ Kf,
    __hip_bfloat16* __restrict__ Vf)
{
    int z = blockIdx.z;
    const __hip_bfloat16* wh = (z==0) ? w0h : (z==1) ? w1h : w2h;
    const __hip_bfloat16* wl = (z==0) ? w0l : (z==1) ? w1l : w2l;
    const float* bias = (z==0) ? bq : (z==1) ? bk : bvv;
    const float sv = (z==0) ? 0.17677669529663687f * 1.4426950408889634f : 1.0f;

    int tid = threadIdx.x;
    int w = tid >> 6, lid = tid & 63, quad = lid >> 4, l15 = lid & 15;
    int row0 = blockIdx.x * 64 + (w >> 1) * 32;
    int col0 = blockIdx.y * 64 + (w & 1) * 32;

    f32x4 acc[2][2] = {};
#pragma unroll
    for (int k0 = 0; k0 < 256; k0 += 32) {
        bf16x8 ah[2], al[2], bh[2], bl[2];
        for (int mi = 0; mi < 2; mi++) {
            size_t ro = (size_t)((row0 + mi * 16) >> 4) * 4096 + (k0 >> 5) * 512 + lid * 8;
            ah[mi] = *(const bf16x8*)(xh + ro);
            al[mi] = *(const bf16x8*)(xl + ro);
        }
        for (int ni = 0; ni < 2; ni++) {
            size_t co = (size_t)((col0 + ni * 16) >> 4) * 4096 + (k0 >> 5) * 512 + lid * 8;
            bh[ni] = *(const bf16x8*)(wh + co);
            bl[ni] = *(const bf16x8*)(wl + co);
        }
        for (int mi = 0; mi < 2; mi++)
            for (int ni = 0; ni < 2; ni++) {
                acc[mi][ni] = mfma_bf16(ah[mi], bh[ni], acc[mi][ni]);
                acc[mi][ni] = mfma_bf16(ah[mi], bl[ni], acc[mi][ni]);
                acc[mi][ni] = mfma_bf16(al[mi], bh[ni], acc[mi][ni]);
            }
    }
    for (int mi = 0; mi < 2; mi++)
        for (int ni = 0; ni < 2; ni++) {
            int col = col0 + ni * 16 + l15;       // D-layout: col = lane&15
            int h = col >> 5, dh = col & 31;
            float bvl = bias[col];
            for (int r = 0; r < 4; r++) {
                int row = row0 + mi * 16 + quad * 4 + r;  // D-layout: row = quad*4+r
                int b = row >> 11, s = row & 2047;
                __hip_bfloat16 o = __float2bfloat16((acc[mi][ni][r] + bvl) * sv);
                size_t bh_base = (size_t)(b * H_ + h) * (S_ * DH_);
                if (z == 2) {
                    int oo = s & 31;
                    int slot = ((oo & 15) >> 2) * 8 + ((oo >> 4) << 2) + (oo & 3);
                    Vf[bh_base + (s >> 5) * 1024 + (dh >> 4) * 512
                       + (slot >> 3) * 128 + (dh & 15) * 8 + (slot & 7)] = o;
                } else {
                    size_t idx = bh_base + (s >> 4) * 512 + (dh >> 3) * 128
                                 + (s & 15) * 8 + (dh & 7);
                    if (z == 0) Qf[idx] = o; else Kf[idx] = o;
                }
            }
        }
}

// ---------------- flash pass, fused combine, q64 per block ----------------
// flat grid 512 blocks, block 256 = 4 waves; XCD-chunked swizzle.
// Block = one q64-tile of (b,h); wave w covers keys w*512..+511 holding FOUR
// q-frags so each K/V load pair feeds 8 QK + 8 PV MFMAs. Partials combined
// in LDS, normalized, written as fragment-linear hi/lo ctx + invL.
__global__ __launch_bounds__(256) void attn_flash(
    const __hip_bfloat16* __restrict__ Qf, const __hip_bfloat16* __restrict__ Kf,
    const __hip_bfloat16* __restrict__ Vf,
    __hip_bfloat16* __restrict__ cth, __hip_bfloat16* __restrict__ ctl,
    float* __restrict__ invL)
{
    __shared__ float sO[KSPLIT][64][33];   // +1 pad: avoid bank conflicts (~34 KB)
    __shared__ float sL[KSPLIT][64];
    int f = blockIdx.x;
    int g = (f & 7) * 64 + (f >> 3);       // chunked XCD swizzle (bijective, 512%8==0)
    int qt = g & 31;
    int h = (g >> 5) & 7;
    int b = g >> 8;
    int q0 = qt * 64;
    int tid = threadIdx.x, w = tid >> 6, lid = tid & 63, quad = lid >> 4, l15 = lid & 15;
    size_t bh_base = (size_t)(b * H_ + h) * (S_ * DH_);
    const __hip_bfloat16* Qp = Qf + bh_base + (q0 >> 4) * 512 + lid * 8;
    const __hip_bfloat16* Kp = Kf + bh_base + lid * 8;
    const __hip_bfloat16* Vp = Vf + bh_base + lid * 8;
    bf16x8 qf[4];                          // q-rows q0+16*i.. (B: n=q, k=dh)
#pragma unroll
    for (int i = 0; i < 4; i++) qf[i] = *(const bf16x8*)(Qp + i * 512);
    f32x4 zacc = {};
    f32x4 oacc[4][2] = {};                 // [qgroup][dh-half]
    float lp[4] = {};

    int kbeg = w * KKEYS;
    for (int k0 = kbeg; k0 < kbeg + KKEYS; k0 += 32) {
        bf16x8 kf0 = *(const bf16x8*)(Kp + (k0 >> 4) * 512);
        bf16x8 kf1 = *(const bf16x8*)(Kp + (k0 >> 4) * 512 + 512);
        bf16x8 vf0 = *(const bf16x8*)(Vp + (k0 >> 5) * 1024);
        bf16x8 vf1 = *(const bf16x8*)(Vp + (k0 >> 5) * 1024 + 512);
#pragma unroll
        for (int qg = 0; qg < 4; qg++) {
            f32x4 c0 = mfma_bf16(kf0, qf[qg], zacc);   // keys k0+quad*4+r,    q=l15
            f32x4 c1 = mfma_bf16(kf1, qf[qg], zacc);   // keys k0+16+quad*4+r
            float e0[4], e1[4];
            for (int r = 0; r < 4; r++) {
                e0[r] = fast_exp2(c0[r]);
                e1[r] = fast_exp2(c1[r]);
            }
            lp[qg] += ((e0[0] + e0[1]) + (e0[2] + e0[3]))
                    + ((e1[0] + e1[1]) + (e1[2] + e1[3]));
            union { bf16x8 v; __hip_bfloat162 h2[4]; } pu;
            pu.h2[0] = __float22bfloat162_rn(make_float2(e0[0], e0[1]));
            pu.h2[1] = __float22bfloat162_rn(make_float2(e0[2], e0[3]));
            pu.h2[2] = __float22bfloat162_rn(make_float2(e1[0], e1[1]));
            pu.h2[3] = __float22bfloat162_rn(make_float2(e1[2], e1[3]));
            oacc[qg][0] = mfma_bf16(vf0, pu.v, oacc[qg][0]);   // d 0..15
            oacc[qg][1] = mfma_bf16(vf1, pu.v, oacc[qg][1]);   // d 16..31
        }
    }
#pragma unroll
    for (int qg = 0; qg < 4; qg++) {
        lp[qg] += __shfl_xor(lp[qg], 16);
        lp[qg] += __shfl_xor(lp[qg], 32);   // all lanes: full 512-key row sum, q=l15
    }

    // stash partials in LDS
#pragma unroll
    for (int qg = 0; qg < 4; qg++)
        for (int dh2 = 0; dh2 < 2; dh2++)
            for (int r = 0; r < 4; r++)
                sO[w][qg * 16 + l15][dh2 * 16 + quad * 4 + r] = oacc[qg][dh2][r];
    if (lid < 16)
        for (int qg = 0; qg < 4; qg++) sL[w][qg * 16 + lid] = lp[qg];
    __syncthreads();

    // combine + normalize + write: 2048 ctx elems / 256 threads = 8 each
    int d = tid & 31, q = tid >> 5;   // q in 0..7
#pragma unroll
    for (int qq = q; qq < 64; qq += 8) {
        float l = (sL[0][qq] + sL[1][qq]) + (sL[2][qq] + sL[3][qq]);
        float o = (sO[0][qq][d] + sO[1][qq][d]) + (sO[2][qq][d] + sO[3][qq][d]);
        float inv = 1.0f / l;
        float val = o * inv;
        size_t fi = fragidx(b * S_ + q0 + qq, h * DH_ + d);
        __hip_bfloat16 hv = __float2bfloat16(val);
        cth[fi] = hv;
        ctl[fi] = __float2bfloat16(val - __bfloat162float(hv));
        if (d == 0) invL[(b * H_ + h) * S_ + q0 + qq] = inv;
    }
}

// ---------------- merged: out projection (blocks 0..255) + attn write (256..767) ----
// out_gemm first so its 256 blocks overlap the attn wave instead of the tail.
// attn blocks (q64 x 256k tiles) XCD-chunk-swizzled by (b,kx).
__global__ __launch_bounds__(256) void attn_out(
    const __hip_bfloat16* __restrict__ Qf, const __hip_bfloat16* __restrict__ Kf,
    const float* __restrict__ invL,
    const __hip_bfloat16* __restrict__ ch, const __hip_bfloat16* __restrict__ cl,
    const __hip_bfloat16* __restrict__ wh, const __hip_bfloat16* __restrict__ wl,
    const float* __restrict__ bias,
    float* __restrict__ attn, float* __restrict__ out)
{
    __shared__ float invbuf[H_ * 64];
    int bid = blockIdx.x;
    int tid = threadIdx.x, w = tid >> 6, lid = tid & 63, quad = lid >> 4, l15 = lid & 15;

    if (bid < 256) {
        // ---- out_gemm: out = ctx @ wc^T + bc (fp32 out), 2x2 wave tiles of 32x32 ----
        int row0 = (bid & 63) * 64 + (w >> 1) * 32;
        int col0 = (bid >> 6) * 64 + (w & 1) * 32;

        f32x4 acc[2][2] = {};
#pragma unroll
        for (int k0 = 0; k0 < 256; k0 += 32) {
            bf16x8 ah[2], al[2], bh[2], bl[2];
            for (int mi = 0; mi < 2; mi++) {
                size_t ro = (size_t)((row0 + mi * 16) >> 4) * 4096 + (k0 >> 5) * 512 + lid * 8;
                ah[mi] = *(const bf16x8*)(ch + ro);
                al[mi] = *(const bf16x8*)(cl + ro);
            }
            for (int ni = 0; ni < 2; ni++) {
                size_t co = (size_t)((col0 + ni * 16) >> 4) * 4096 + (k0 >> 5) * 512 + lid * 8;
                bh[ni] = *(const bf16x8*)(wh + co);
                bl[ni] = *(const bf16x8*)(wl + co);
            }
            for (int mi = 0; mi < 2; mi++)
                for (int ni = 0; ni < 2; ni++) {
                    acc[mi][ni] = mfma_bf16(ah[mi], bh[ni], acc[mi][ni]);
                    acc[mi][ni] = mfma_bf16(ah[mi], bl[ni], acc[mi][ni]);
                    acc[mi][ni] = mfma_bf16(al[mi], bh[ni], acc[mi][ni]);
                }
        }
        for (int mi = 0; mi < 2; mi++)
            for (int ni = 0; ni < 2; ni++) {
                int col = col0 + ni * 16 + l15;
                float bvl = bias[col];
                for (int r = 0; r < 4; r++) {
                    int row = row0 + mi * 16 + quad * 4 + r;
                    out[(size_t)row * 256 + col] = acc[mi][ni][r] + bvl;
                }
            }
    } else {
        // ---- attn write: head-mean probs, 64q x 256k per block ----
        int f2 = bid - 256;                      // 256 % 8 == 0: f2&7 preserves XCD
        int g = (f2 & 7) * 64 + (f2 >> 3);       // chunked XCD swizzle (bijective)
        int qy = g & 31, kx = (g >> 5) & 7, b = g >> 8;
        int q0 = qy * 64;
        int k0 = kx * 256 + w * 64;
        invbuf[tid] = invL[(b * H_ + (tid >> 6)) * S_ + q0 + (tid & 63)] * 0.125f;
        invbuf[tid + 256] =
            invL[(b * H_ + 4 + (tid >> 6)) * S_ + q0 + (tid & 63)] * 0.125f;
        __syncthreads();
        f32x4 zacc = {};
        float psum[4][4][4] = {};                // [qgroup][ktile][r]
        size_t bh0 = (size_t)b * H_ * (S_ * DH_);
        size_t qoff = (size_t)(q0 >> 4) * 512 + lid * 8;
        size_t koff = (size_t)(k0 >> 4) * 512 + lid * 8;

        for (int h = 0; h < H_; h++) {
            size_t nb = bh0 + (size_t)h * (S_ * DH_);
            bf16x8 kf0 = *(const bf16x8*)(Kf + nb + koff);
            bf16x8 kf1 = *(const bf16x8*)(Kf + nb + koff + 512);
            bf16x8 kf2 = *(const bf16x8*)(Kf + nb + koff + 1024);
            bf16x8 kf3 = *(const bf16x8*)(Kf + nb + koff + 1536);
#pragma unroll
            for (int qg = 0; qg < 4; qg++) {
                bf16x8 qfg = *(const bf16x8*)(Qf + nb + qoff + qg * 512);
                float il[4];
                for (int r = 0; r < 4; r++)
                    il[r] = invbuf[h * 64 + qg * 16 + quad * 4 + r];
                f32x4 c0 = mfma_bf16(qfg, kf0, zacc);  // C: row=q (quad*4+r), col=key
                f32x4 c1 = mfma_bf16(qfg, kf1, zacc);
                f32x4 c2 = mfma_bf16(qfg, kf2, zacc);
                f32x4 c3 = mfma_bf16(qfg, kf3, zacc);
                for (int r = 0; r < 4; r++) {
                    psum[qg][0][r] += fast_exp2(c0[r]) * il[r];
                    psum[qg][1][r] += fast_exp2(c1[r]) * il[r];
                    psum[qg][2][r] += fast_exp2(c2[r]) * il[r];
                    psum[qg][3][r] += fast_exp2(c3[r]) * il[r];
                }
            }
        }
#pragma unroll
        for (int qg = 0; qg < 4; qg++)
            for (int nt = 0; nt < 4; nt++)
                for (int r = 0; r < 4; r++)
                    attn[(size_t)(b * S_ + q0 + qg * 16 + quad * 4 + r) * S_
                         + k0 + nt * 16 + l15] = psum[qg][nt][r];
    }
}

extern "C" void kernel_launch(void* const* d_in, const int* in_sizes, int n_in,
                              void* d_out, int out_size, void* d_ws, size_t ws_size,
                              hipStream_t stream) {
    const float* x  = (const float*)d_in[0];
    const float* wq = (const float*)d_in[1];
    const float* bq = (const float*)d_in[2];
    const float* wk = (const float*)d_in[3];
    const float* bk = (const float*)d_in[4];
    const float* wv = (const float*)d_in[5];
    const float* bv = (const float*)d_in[6];
    const float* wc = (const float*)d_in[7];
    const float* bc = (const float*)d_in[8];

    char* ws = (char*)d_ws;
    const size_t MB = 1u << 20;
    const size_t KB128 = 128u * 1024u;
    __hip_bfloat16* xh  = (__hip_bfloat16*)(ws + 0 * MB);
    __hip_bfloat16* xl  = (__hip_bfloat16*)(ws + 2 * MB);
    __hip_bfloat16* wqh = (__hip_bfloat16*)(ws + 4 * MB + 0 * KB128);
    __hip_bfloat16* wql = (__hip_bfloat16*)(ws + 4 * MB + 1 * KB128);
    __hip_bfloat16* wkh = (__hip_bfloat16*)(ws + 4 * MB + 2 * KB128);
    __hip_bfloat16* wkl = (__hip_bfloat16*)(ws + 4 * MB + 3 * KB128);
    __hip_bfloat16* wvh = (__hip_bfloat16*)(ws + 4 * MB + 4 * KB128);
    __hip_bfloat16* wvl = (__hip_bfloat16*)(ws + 4 * MB + 5 * KB128);
    __hip_bfloat16* wch = (__hip_bfloat16*)(ws + 4 * MB + 6 * KB128);
    __hip_bfloat16* wcl = (__hip_bfloat16*)(ws + 4 * MB + 7 * KB128);
    __hip_bfloat16* Qfb = (__hip_bfloat16*)(ws + 5 * MB);
    __hip_bfloat16* Kfb = (__hip_bfloat16*)(ws + 7 * MB);
    __hip_bfloat16* Vfb = (__hip_bfloat16*)(ws + 9 * MB);
    __hip_bfloat16* cth = (__hip_bfloat16*)(ws + 11 * MB);
    __hip_bfloat16* ctl = (__hip_bfloat16*)(ws + 13 * MB);
    float* invL  = (float*)(ws + 15 * MB);                    // 128 KB

    float* outp  = (float*)d_out;
    float* attnp = outp + (size_t)NROW * D_;  // outputs concatenated: out, attention

    hipLaunchKernelGGL(split_all, dim3(1280), dim3(256), 0, stream,
                       (const float4*)x, (const float4*)wq, (const float4*)wk,
                       (const float4*)wv, (const float4*)wc,
                       (ushort4*)xh, (ushort4*)xl,
                       (ushort4*)wqh, (ushort4*)wql, (ushort4*)wkh, (ushort4*)wkl,
                       (ushort4*)wvh, (ushort4*)wvl, (ushort4*)wch, (ushort4*)wcl);

    hipLaunchKernelGGL(qkv_gemm, dim3(NROW / 64, 4, 3), dim3(256), 0, stream,
                       xh, xl, wqh, wql, wkh, wkl, wvh, wvl, bq, bk, bv, Qfb, Kfb, Vfb);

    hipLaunchKernelGGL(attn_flash, dim3(512), dim3(256), 0, stream,
                       Qfb, Kfb, Vfb, cth, ctl, invL);

    hipLaunchKernelGGL(attn_out, dim3(256 + 512), dim3(256), 0, stream,
                       Qfb, Kfb, invL, cth, ctl, wch, wcl, bc, attnp, outp);
}

// Round 6
// 126.921 us; speedup vs baseline: 1.0657x; 1.0657x over previous
//
#include <hip/hip_runtime.h>
#include <hip/hip_bf16.h>

// MHA fwd: B=2, S=2048, D=256, H=8, Dh=32.
// Outputs: out [2,2048,256] fp32, attn_mean [2,2048,2048] fp32 (concat in d_out).
//
// R13: exact revert to R11 champion (127.0 us).
// R12 (q64 tiles) regressed +8.2us: grid fell to 512/768 blocks (2-3/CU) and
// per-wave state ~doubled -> occupancy-driven loss swamped the reuse gain.
// Ledger: traffic/VMEM-work reduction pays ONLY while >=4 blocks/CU.
// q32 tiles + 1024-block grids is the sweet spot for S=2048,B=2.

#define B_   2
#define S_   2048
#define D_   256
#define H_   8
#define DH_  32
#define NROW (B_*S_)      // 4096
#define KSPLIT 4
#define KKEYS (S_/KSPLIT) // 512

typedef __attribute__((ext_vector_type(8))) short bf16x8;  // 8 bf16 (4 VGPRs)
typedef __attribute__((ext_vector_type(4))) float f32x4;

__device__ __forceinline__ f32x4 mfma_bf16(bf16x8 a, bf16x8 b, f32x4 c) {
    return __builtin_amdgcn_mfma_f32_16x16x32_bf16(a, b, c, 0, 0, 0);
}

__device__ __forceinline__ float fast_exp2(float x) {
    return __builtin_amdgcn_exp2f(x);   // v_exp_f32
}

__device__ __forceinline__ unsigned short f2bf_bits(float v) {
    __hip_bfloat16 h = __float2bfloat16(v);
    return *reinterpret_cast<unsigned short*>(&h);
}

// fragment-linear index for a row-major [R x 256] matrix element (m, k)
__device__ __forceinline__ size_t fragidx(int m, int k) {
    return (size_t)(m >> 4) * 4096 + (k >> 5) * 512 + ((k >> 3) & 3) * 128
           + (m & 15) * 8 + (k & 7);
}

// ---------------- split fp32 -> (hi, lo) bf16, fragment-linear, one launch ----------------
__global__ void split_all(const float4* __restrict__ x,
                          const float4* __restrict__ wq, const float4* __restrict__ wk,
                          const float4* __restrict__ wv, const float4* __restrict__ wc,
                          ushort4* __restrict__ xh, ushort4* __restrict__ xl,
                          ushort4* __restrict__ wqh, ushort4* __restrict__ wql,
                          ushort4* __restrict__ wkh, ushort4* __restrict__ wkl,
                          ushort4* __restrict__ wvh, ushort4* __restrict__ wvl,
                          ushort4* __restrict__ wch, ushort4* __restrict__ wcl) {
    int i = blockIdx.x * 256 + threadIdx.x;   // total 327680 float4s
    const float4* src; ushort4 *ph, *pl; int off;
    if (i < 262144) { src = x; ph = xh; pl = xl; off = i; }
    else {
        int j = i - 262144;
        int rg = j >> 14; off = j & 16383;
        if (rg == 0)      { src = wq; ph = wqh; pl = wql; }
        else if (rg == 1) { src = wk; ph = wkh; pl = wkl; }
        else if (rg == 2) { src = wv; ph = wvh; pl = wvl; }
        else              { src = wc; ph = wch; pl = wcl; }
    }
    float4 v = src[off];
    float vv[4] = {v.x, v.y, v.z, v.w};
    ushort4 hb, lb;
    unsigned short* hp = (unsigned short*)&hb;
    unsigned short* lp = (unsigned short*)&lb;
    for (int c = 0; c < 4; c++) {
        __hip_bfloat16 h = __float2bfloat16(vv[c]);
        hp[c] = *reinterpret_cast<unsigned short*>(&h);
        lp[c] = f2bf_bits(vv[c] - __bfloat162float(h));
    }
    int m = off >> 6, k = (off & 63) * 4;
    size_t fi = fragidx(m, k);          // divisible by 4
    ph[fi >> 2] = hb;
    pl[fi >> 2] = lb;
}

// ---------------- QKV projection: y = x @ W^T + b ----------------
// grid (NROW/64=64, 4, 3), block 256 (4 waves, 2x2 wave tiles of 32x32).
__global__ __launch_bounds__(256) void qkv_gemm(
    const __hip_bfloat16* __restrict__ xh, const __hip_bfloat16* __restrict__ xl,
    const __hip_bfloat16* __restrict__ w0h, const __hip_bfloat16* __restrict__ w0l,
    const __hip_bfloat16* __restrict__ w1h, const __hip_bfloat16* __restrict__ w1l,
    const __hip_bfloat16* __restrict__ w2h, const __hip_bfloat16* __restrict__ w2l,
    const float* __restrict__ bq, const float* __restrict__ bk, const float* __restrict__ bvv,
    __hip_bfloat16* __restrict__ Qf, __hip_bfloat16* __restrict__ Kf,
    __hip_bfloat16* __restrict__ Vf)
{
    int z = blockIdx.z;
    const __hip_bfloat16* wh = (z==0) ? w0h : (z==1) ? w1h : w2h;
    const __hip_bfloat16* wl = (z==0) ? w0l : (z==1) ? w1l : w2l;
    const float* bias = (z==0) ? bq : (z==1) ? bk : bvv;
    const float sv = (z==0) ? 0.17677669529663687f * 1.4426950408889634f : 1.0f;

    int tid = threadIdx.x;
    int w = tid >> 6, lid = tid & 63, quad = lid >> 4, l15 = lid & 15;
    int row0 = blockIdx.x * 64 + (w >> 1) * 32;
    int col0 = blockIdx.y * 64 + (w & 1) * 32;

    f32x4 acc[2][2] = {};
#pragma unroll
    for (int k0 = 0; k0 < 256; k0 += 32) {
        bf16x8 ah[2], al[2], bh[2], bl[2];
        for (int mi = 0; mi < 2; mi++) {
            size_t ro = (size_t)((row0 + mi * 16) >> 4) * 4096 + (k0 >> 5) * 512 + lid * 8;
            ah[mi] = *(const bf16x8*)(xh + ro);
            al[mi] = *(const bf16x8*)(xl + ro);
        }
        for (int ni = 0; ni < 2; ni++) {
            size_t co = (size_t)((col0 + ni * 16) >> 4) * 4096 + (k0 >> 5) * 512 + lid * 8;
            bh[ni] = *(const bf16x8*)(wh + co);
            bl[ni] = *(const bf16x8*)(wl + co);
        }
        for (int mi = 0; mi < 2; mi++)
            for (int ni = 0; ni < 2; ni++) {
                acc[mi][ni] = mfma_bf16(ah[mi], bh[ni], acc[mi][ni]);
                acc[mi][ni] = mfma_bf16(ah[mi], bl[ni], acc[mi][ni]);
                acc[mi][ni] = mfma_bf16(al[mi], bh[ni], acc[mi][ni]);
            }
    }
    for (int mi = 0; mi < 2; mi++)
        for (int ni = 0; ni < 2; ni++) {
            int col = col0 + ni * 16 + l15;       // D-layout: col = lane&15
            int h = col >> 5, dh = col & 31;
            float bvl = bias[col];
            for (int r = 0; r < 4; r++) {
                int row = row0 + mi * 16 + quad * 4 + r;  // D-layout: row = quad*4+r
                int b = row >> 11, s = row & 2047;
                __hip_bfloat16 o = __float2bfloat16((acc[mi][ni][r] + bvl) * sv);
                size_t bh_base = (size_t)(b * H_ + h) * (S_ * DH_);
                if (z == 2) {
                    int oo = s & 31;
                    int slot = ((oo & 15) >> 2) * 8 + ((oo >> 4) << 2) + (oo & 3);
                    Vf[bh_base + (s >> 5) * 1024 + (dh >> 4) * 512
                       + (slot >> 3) * 128 + (dh & 15) * 8 + (slot & 7)] = o;
                } else {
                    size_t idx = bh_base + (s >> 4) * 512 + (dh >> 3) * 128
                                 + (s & 15) * 8 + (dh & 7);
                    if (z == 0) Qf[idx] = o; else Kf[idx] = o;
                }
            }
        }
}

// ---------------- flash pass, fused combine, q32 per block ----------------
// flat grid 1024 blocks, block 256 = 4 waves; XCD-chunked swizzle.
// Block = one q32-tile of (b,h); wave w covers keys w*512..+511 holding TWO
// q-frags so each K/V load feeds 2 QK + 2 PV MFMAs. Partials combined in
// LDS, normalized, written as fragment-linear hi/lo ctx + invL.
__global__ __launch_bounds__(256) void attn_flash(
    const __hip_bfloat16* __restrict__ Qf, const __hip_bfloat16* __restrict__ Kf,
    const __hip_bfloat16* __restrict__ Vf,
    __hip_bfloat16* __restrict__ cth, __hip_bfloat16* __restrict__ ctl,
    float* __restrict__ invL)
{
    __shared__ float sO[KSPLIT][32][33];   // +1 pad: avoid bank conflicts
    __shared__ float sL[KSPLIT][32];
    int f = blockIdx.x;
    int g = (f & 7) * 128 + (f >> 3);      // chunked XCD swizzle (bijective, 1024%8==0)
    int qt = g & 63;
    int h = (g >> 6) & 7;
    int b = g >> 9;
    int q0 = qt * 32;
    int tid = threadIdx.x, w = tid >> 6, lid = tid & 63, quad = lid >> 4, l15 = lid & 15;
    size_t bh_base = (size_t)(b * H_ + h) * (S_ * DH_);
    const __hip_bfloat16* Qp = Qf + bh_base + (q0 >> 4) * 512 + lid * 8;
    const __hip_bfloat16* Kp = Kf + bh_base + lid * 8;
    const __hip_bfloat16* Vp = Vf + bh_base + lid * 8;
    bf16x8 qfA = *(const bf16x8*)Qp;          // q-rows q0..q0+15   (B: n=q, k=dh)
    bf16x8 qfB = *(const bf16x8*)(Qp + 512);  // q-rows q0+16..q0+31
    f32x4 zacc = {};
    f32x4 oacc[2][2] = {};                    // [qgroup][dh-half]
    float lpA = 0.f, lpB = 0.f;

    int kbeg = w * KKEYS;
#pragma unroll 2
    for (int k0 = kbeg; k0 < kbeg + KKEYS; k0 += 32) {
        bf16x8 kf0 = *(const bf16x8*)(Kp + (k0 >> 4) * 512);
        bf16x8 kf1 = *(const bf16x8*)(Kp + (k0 >> 4) * 512 + 512);
        bf16x8 vf0 = *(const bf16x8*)(Vp + (k0 >> 5) * 1024);
        bf16x8 vf1 = *(const bf16x8*)(Vp + (k0 >> 5) * 1024 + 512);

        __builtin_amdgcn_s_setprio(1);
        f32x4 cA0 = mfma_bf16(kf0, qfA, zacc);   // keys k0+quad*4+r,    q=l15 (group A)
        f32x4 cA1 = mfma_bf16(kf1, qfA, zacc);   // keys k0+16+quad*4+r
        f32x4 cB0 = mfma_bf16(kf0, qfB, zacc);   // group B
        f32x4 cB1 = mfma_bf16(kf1, qfB, zacc);
        __builtin_amdgcn_s_setprio(0);
        float eA0[4], eA1[4], eB0[4], eB1[4];
        for (int r = 0; r < 4; r++) {
            eA0[r] = fast_exp2(cA0[r]);
            eA1[r] = fast_exp2(cA1[r]);
            eB0[r] = fast_exp2(cB0[r]);
            eB1[r] = fast_exp2(cB1[r]);
        }
        lpA += eA0[0] + eA0[1] + eA0[2] + eA0[3] + eA1[0] + eA1[1] + eA1[2] + eA1[3];
        lpB += eB0[0] + eB0[1] + eB0[2] + eB0[3] + eB1[0] + eB1[1] + eB1[2] + eB1[3];
        union { bf16x8 v; __hip_bfloat162 h2[4]; } puA, puB;
        puA.h2[0] = __float22bfloat162_rn(make_float2(eA0[0], eA0[1]));
        puA.h2[1] = __float22bfloat162_rn(make_float2(eA0[2], eA0[3]));
        puA.h2[2] = __float22bfloat162_rn(make_float2(eA1[0], eA1[1]));
        puA.h2[3] = __float22bfloat162_rn(make_float2(eA1[2], eA1[3]));
        puB.h2[0] = __float22bfloat162_rn(make_float2(eB0[0], eB0[1]));
        puB.h2[1] = __float22bfloat162_rn(make_float2(eB0[2], eB0[3]));
        puB.h2[2] = __float22bfloat162_rn(make_float2(eB1[0], eB1[1]));
        puB.h2[3] = __float22bfloat162_rn(make_float2(eB1[2], eB1[3]));
        __builtin_amdgcn_s_setprio(1);
        oacc[0][0] = mfma_bf16(vf0, puA.v, oacc[0][0]);   // d 0..15
        oacc[0][1] = mfma_bf16(vf1, puA.v, oacc[0][1]);   // d 16..31
        oacc[1][0] = mfma_bf16(vf0, puB.v, oacc[1][0]);
        oacc[1][1] = mfma_bf16(vf1, puB.v, oacc[1][1]);
        __builtin_amdgcn_s_setprio(0);
    }
    lpA += __shfl_xor(lpA, 16);
    lpA += __shfl_xor(lpA, 32);   // all lanes: full 512-key row sum for q=l15 (group A)
    lpB += __shfl_xor(lpB, 16);
    lpB += __shfl_xor(lpB, 32);

    // stash partials in LDS
    for (int qg = 0; qg < 2; qg++)
        for (int dh2 = 0; dh2 < 2; dh2++)
            for (int r = 0; r < 4; r++)
                sO[w][qg * 16 + l15][dh2 * 16 + quad * 4 + r] = oacc[qg][dh2][r];
    if (lid < 16) { sL[w][lid] = lpA; sL[w][16 + lid] = lpB; }
    __syncthreads();

    // combine + normalize + write: 1024 ctx elems / 256 threads = 4 each
    int d = tid & 31, q = tid >> 5;   // q in 0..7
#pragma unroll
    for (int qq = q; qq < 32; qq += 8) {
        float l = sL[0][qq] + sL[1][qq] + sL[2][qq] + sL[3][qq];
        float o = sO[0][qq][d] + sO[1][qq][d] + sO[2][qq][d] + sO[3][qq][d];
        float inv = 1.0f / l;
        float val = o * inv;
        size_t fi = fragidx(b * S_ + q0 + qq, h * DH_ + d);
        __hip_bfloat16 hv = __float2bfloat16(val);
        cth[fi] = hv;
        ctl[fi] = __float2bfloat16(val - __bfloat162float(hv));
        if (d == 0) invL[(b * H_ + h) * S_ + q0 + qq] = inv;
    }
}

// ---------------- merged: out projection (blocks 0..255) + attn write (256..1279) ----
// out_gemm first so its 256 blocks overlap the attn wave instead of the tail.
// attn blocks (q32 x 256k tiles) XCD-chunk-swizzled by (b,kx).
__global__ __launch_bounds__(256) void attn_out(
    const __hip_bfloat16* __restrict__ Qf, const __hip_bfloat16* __restrict__ Kf,
    const float* __restrict__ invL,
    const __hip_bfloat16* __restrict__ ch, const __hip_bfloat16* __restrict__ cl,
    const __hip_bfloat16* __restrict__ wh, const __hip_bfloat16* __restrict__ wl,
    const float* __restrict__ bias,
    float* __restrict__ attn, float* __restrict__ out)
{
    __shared__ float invbuf[H_ * 32];
    int bid = blockIdx.x;
    int tid = threadIdx.x, w = tid >> 6, lid = tid & 63, quad = lid >> 4, l15 = lid & 15;

    if (bid < 256) {
        // ---- out_gemm: out = ctx @ wc^T + bc (fp32 out), 2x2 wave tiles of 32x32 ----
        int row0 = (bid & 63) * 64 + (w >> 1) * 32;
        int col0 = (bid >> 6) * 64 + (w & 1) * 32;

        f32x4 acc[2][2] = {};
#pragma unroll
        for (int k0 = 0; k0 < 256; k0 += 32) {
            bf16x8 ah[2], al[2], bh[2], bl[2];
            for (int mi = 0; mi < 2; mi++) {
                size_t ro = (size_t)((row0 + mi * 16) >> 4) * 4096 + (k0 >> 5) * 512 + lid * 8;
                ah[mi] = *(const bf16x8*)(ch + ro);
                al[mi] = *(const bf16x8*)(cl + ro);
            }
            for (int ni = 0; ni < 2; ni++) {
                size_t co = (size_t)((col0 + ni * 16) >> 4) * 4096 + (k0 >> 5) * 512 + lid * 8;
                bh[ni] = *(const bf16x8*)(wh + co);
                bl[ni] = *(const bf16x8*)(wl + co);
            }
            for (int mi = 0; mi < 2; mi++)
                for (int ni = 0; ni < 2; ni++) {
                    acc[mi][ni] = mfma_bf16(ah[mi], bh[ni], acc[mi][ni]);
                    acc[mi][ni] = mfma_bf16(ah[mi], bl[ni], acc[mi][ni]);
                    acc[mi][ni] = mfma_bf16(al[mi], bh[ni], acc[mi][ni]);
                }
        }
        for (int mi = 0; mi < 2; mi++)
            for (int ni = 0; ni < 2; ni++) {
                int col = col0 + ni * 16 + l15;
                float bvl = bias[col];
                for (int r = 0; r < 4; r++) {
                    int row = row0 + mi * 16 + quad * 4 + r;
                    out[(size_t)row * 256 + col] = acc[mi][ni][r] + bvl;
                }
            }
    } else {
        // ---- attn write: head-mean probs, 32q x 256k per block ----
        int f2 = bid - 256;                       // 256 % 8 == 0: f2&7 preserves XCD
        int g = (f2 & 7) * 128 + (f2 >> 3);       // chunked XCD swizzle (bijective)
        int qy = g & 63, kx = (g >> 6) & 7, b = g >> 9;
        int q0 = qy * 32;
        int k0 = kx * 256 + w * 64;
        invbuf[tid] = invL[(b * H_ + (tid >> 5)) * S_ + q0 + (tid & 31)] * 0.125f; // fold 1/H
        __syncthreads();
        f32x4 zacc = {};
        float psum[2][4][4] = {};                 // [qgroup][ktile][r]
        size_t bh0 = (size_t)b * H_ * (S_ * DH_);
        size_t qoff = (size_t)(q0 >> 4) * 512 + lid * 8;
        size_t koff = (size_t)(k0 >> 4) * 512 + lid * 8;

#pragma unroll 2
        for (int h = 0; h < H_; h++) {
            size_t nb = bh0 + (size_t)h * (S_ * DH_);
            bf16x8 qfA = *(const bf16x8*)(Qf + nb + qoff);          // A: row=q (group A)
            bf16x8 qfB = *(const bf16x8*)(Qf + nb + qoff + 512);    // group B
            bf16x8 kf0 = *(const bf16x8*)(Kf + nb + koff);
            bf16x8 kf1 = *(const bf16x8*)(Kf + nb + koff + 512);
            bf16x8 kf2 = *(const bf16x8*)(Kf + nb + koff + 1024);
            bf16x8 kf3 = *(const bf16x8*)(Kf + nb + koff + 1536);

            float ilA[4], ilB[4];
            for (int r = 0; r < 4; r++) {
                ilA[r] = invbuf[h * 32 + quad * 4 + r];
                ilB[r] = invbuf[h * 32 + 16 + quad * 4 + r];
            }

            __builtin_amdgcn_s_setprio(1);
            f32x4 cA0 = mfma_bf16(qfA, kf0, zacc);  // C: row=q (quad*4+r), col=key (l15)
            f32x4 cA1 = mfma_bf16(qfA, kf1, zacc);
            f32x4 cA2 = mfma_bf16(qfA, kf2, zacc);
            f32x4 cA3 = mfma_bf16(qfA, kf3, zacc);
            f32x4 cB0 = mfma_bf16(qfB, kf0, zacc);
            f32x4 cB1 = mfma_bf16(qfB, kf1, zacc);
            f32x4 cB2 = mfma_bf16(qfB, kf2, zacc);
            f32x4 cB3 = mfma_bf16(qfB, kf3, zacc);
            __builtin_amdgcn_s_setprio(0);
            for (int r = 0; r < 4; r++) {
                psum[0][0][r] += fast_exp2(cA0[r]) * ilA[r];
                psum[0][1][r] += fast_exp2(cA1[r]) * ilA[r];
                psum[0][2][r] += fast_exp2(cA2[r]) * ilA[r];
                psum[0][3][r] += fast_exp2(cA3[r]) * ilA[r];
                psum[1][0][r] += fast_exp2(cB0[r]) * ilB[r];
                psum[1][1][r] += fast_exp2(cB1[r]) * ilB[r];
                psum[1][2][r] += fast_exp2(cB2[r]) * ilB[r];
                psum[1][3][r] += fast_exp2(cB3[r]) * ilB[r];
            }
        }
        for (int qg = 0; qg < 2; qg++)
            for (int nt = 0; nt < 4; nt++)
                for (int r = 0; r < 4; r++)
                    attn[(size_t)(b * S_ + q0 + qg * 16 + quad * 4 + r) * S_
                         + k0 + nt * 16 + l15] = psum[qg][nt][r];
    }
}

extern "C" void kernel_launch(void* const* d_in, const int* in_sizes, int n_in,
                              void* d_out, int out_size, void* d_ws, size_t ws_size,
                              hipStream_t stream) {
    const float* x  = (const float*)d_in[0];
    const float* wq = (const float*)d_in[1];
    const float* bq = (const float*)d_in[2];
    const float* wk = (const float*)d_in[3];
    const float* bk = (const float*)d_in[4];
    const float* wv = (const float*)d_in[5];
    const float* bv = (const float*)d_in[6];
    const float* wc = (const float*)d_in[7];
    const float* bc = (const float*)d_in[8];

    char* ws = (char*)d_ws;
    const size_t MB = 1u << 20;
    const size_t KB128 = 128u * 1024u;
    __hip_bfloat16* xh  = (__hip_bfloat16*)(ws + 0 * MB);
    __hip_bfloat16* xl  = (__hip_bfloat16*)(ws + 2 * MB);
    __hip_bfloat16* wqh = (__hip_bfloat16*)(ws + 4 * MB + 0 * KB128);
    __hip_bfloat16* wql = (__hip_bfloat16*)(ws + 4 * MB + 1 * KB128);
    __hip_bfloat16* wkh = (__hip_bfloat16*)(ws + 4 * MB + 2 * KB128);
    __hip_bfloat16* wkl = (__hip_bfloat16*)(ws + 4 * MB + 3 * KB128);
    __hip_bfloat16* wvh = (__hip_bfloat16*)(ws + 4 * MB + 4 * KB128);
    __hip_bfloat16* wvl = (__hip_bfloat16*)(ws + 4 * MB + 5 * KB128);
    __hip_bfloat16* wch = (__hip_bfloat16*)(ws + 4 * MB + 6 * KB128);
    __hip_bfloat16* wcl = (__hip_bfloat16*)(ws + 4 * MB + 7 * KB128);
    __hip_bfloat16* Qfb = (__hip_bfloat16*)(ws + 5 * MB);
    __hip_bfloat16* Kfb = (__hip_bfloat16*)(ws + 7 * MB);
    __hip_bfloat16* Vfb = (__hip_bfloat16*)(ws + 9 * MB);
    __hip_bfloat16* cth = (__hip_bfloat16*)(ws + 11 * MB);
    __hip_bfloat16* ctl = (__hip_bfloat16*)(ws + 13 * MB);
    float* invL  = (float*)(ws + 15 * MB);                    // 128 KB

    float* outp  = (float*)d_out;
    float* attnp = outp + (size_t)NROW * D_;  // outputs concatenated: out, attention

    hipLaunchKernelGGL(split_all, dim3(1280), dim3(256), 0, stream,
                       (const float4*)x, (const float4*)wq, (const float4*)wk,
                       (const float4*)wv, (const float4*)wc,
                       (ushort4*)xh, (ushort4*)xl,
                       (ushort4*)wqh, (ushort4*)wql, (ushort4*)wkh, (ushort4*)wkl,
                       (ushort4*)wvh, (ushort4*)wvl, (ushort4*)wch, (ushort4*)wcl);

    hipLaunchKernelGGL(qkv_gemm, dim3(NROW / 64, 4, 3), dim3(256), 0, stream,
                       xh, xl, wqh, wql, wkh, wkl, wvh, wvl, bq, bk, bv, Qfb, Kfb, Vfb);

    hipLaunchKernelGGL(attn_flash, dim3(1024), dim3(256), 0, stream,
                       Qfb, Kfb, Vfb, cth, ctl, invL);

    hipLaunchKernelGGL(attn_out, dim3(256 + 1024), dim3(256), 0, stream,
                       Qfb, Kfb, invL, cth, ctl, wch, wcl, bc, attnp, outp);
}